// Round 1
// baseline (516.352 us; speedup 1.0000x reference)
//
#include <hip/hip_runtime.h>
#include <math.h>

// QAPR_Net forward. Constants from reference:
#define NWAY 5
#define KSHOT 5
#define PRJ 14
#define DD 64
#define PP 100        // H*W
#define NQ 1024
#define NS 350        // NWAY*KSHOT*PRJ
#define NPAIR 70      // NWAY*PRJ
#define LAMDA 32.0f
#define MARGIN 0.3f

// ---- workspace layout (floats) ----
#define VPT_OFF   0          // [70][100][64] = 448000
#define VNINV_OFF 448000     // [70] (pad to 128)
#define BASE_OFF  448128     // [5][64] = 320
#define QV_OFF    448448     // [1024][64] = 65536
#define INVQ_OFF  513984     // [1024][100] = 102400
#define SIM_OFF   616384     // [1024][70] = 71680
#define PW_OFF    688064     // [1024][70] = 71680
#define PQ_OFF    759744     // [1024][5][64] = 327680
#define CLS_OFF   1087424    // [1024]
#define ALN_OFF   1088448    // [1024]

__device__ __forceinline__ float redsum64(float x){
  #pragma unroll
  for (int o = 1; o < 64; o <<= 1) x += __shfl_xor(x, o, 64);
  return x;
}

// ---------------- kernel V: support normalize + view_proto [pair][p][d] + vninv ----------------
__global__ __launch_bounds__(256) void kV(const float* __restrict__ feat,
                                          float* __restrict__ vpt,
                                          float* __restrict__ vninv){
  __shared__ float lds[64*101];
  __shared__ float inv[100];
  __shared__ float red[4];
  int pair = blockIdx.x;            // 0..69
  int n = pair / PRJ, v = pair - n*PRJ;
  int t = threadIdx.x;
  float acc[25];
  #pragma unroll
  for (int i = 0; i < 25; i++) acc[i] = 0.f;

  for (int k = 0; k < KSHOT; k++){
    int s = (n*KSHOT + k)*PRJ + v;
    const float* fp = feat + (size_t)s * 6400;
    #pragma unroll
    for (int i = 0; i < 25; i++){
      int j = t + 256*i;
      int d = j / 100, p = j - d*100;
      lds[d*101 + p] = fp[j];
    }
    __syncthreads();
    if (t < 100){
      float ss = 0.f;
      #pragma unroll
      for (int d = 0; d < 64; d++){ float x = lds[d*101 + t]; ss += x*x; }
      inv[t] = 1.f / fmaxf(sqrtf(ss), 1e-12f);
    }
    __syncthreads();
    #pragma unroll
    for (int i = 0; i < 25; i++){
      int j = t + 256*i;
      int p = j >> 6, d = j & 63;
      acc[i] += lds[d*101 + p] * inv[p];
    }
    __syncthreads();   // before next k overwrites lds/inv
  }
  float ssq = 0.f;
  #pragma unroll
  for (int i = 0; i < 25; i++){
    int j = t + 256*i;
    float val = acc[i] * 0.2f;     // mean over KSHOT=5
    vpt[(size_t)pair*6400 + j] = val;
    ssq += val*val;
  }
  ssq = redsum64(ssq);
  if ((t & 63) == 0) red[t >> 6] = ssq;
  __syncthreads();
  if (t == 0){
    float tot = red[0] + red[1] + red[2] + red[3];
    vninv[pair] = 1.f / fmaxf(sqrtf(tot), 1e-12f);
  }
}

// ---------------- kernel B: base[n][d] = mean over v,p ----------------
__global__ __launch_bounds__(64) void kB(const float* __restrict__ vpt,
                                         float* __restrict__ base){
  int n = blockIdx.x, d = threadIdx.x;
  float s = 0.f;
  for (int v = 0; v < PRJ; v++)
    for (int p = 0; p < PP; p++)
      s += vpt[((n*PRJ + v)*PP + p)*64 + d];
  base[n*64 + d] = s * (1.f/1400.f);
}

// ---------------- kernel Q: per-query inv norms + query_vec ----------------
__global__ __launch_bounds__(256) void kQ(const float* __restrict__ feat,
                                          float* __restrict__ invq,
                                          float* __restrict__ qv){
  __shared__ float lds[64*101];
  __shared__ float inv[100];
  int q = blockIdx.x, t = threadIdx.x;
  const float* fp = feat + (size_t)(NS + q) * 6400;
  #pragma unroll
  for (int i = 0; i < 25; i++){
    int j = t + 256*i;
    int d = j / 100, p = j - d*100;
    lds[d*101 + p] = fp[j];
  }
  __syncthreads();
  if (t < 100){
    float ss = 0.f;
    #pragma unroll
    for (int d = 0; d < 64; d++){ float x = lds[d*101 + t]; ss += x*x; }
    float iv = 1.f / fmaxf(sqrtf(ss), 1e-12f);
    inv[t] = iv;
    invq[q*100 + t] = iv;
  }
  __syncthreads();
  if (t < 64){
    float s = 0.f;
    for (int p = 0; p < PP; p++) s += lds[t*101 + p] * inv[p];
    qv[q*64 + t] = s * 0.01f;
  }
}

// ---------------- kernel S: sim[q][pair] raw dot, 8q x 8pair register GEMM ----------------
__global__ __launch_bounds__(256) void kS(const float* __restrict__ feat,
                                          const float* __restrict__ invq,
                                          const float* __restrict__ vpt,
                                          float* __restrict__ sim){
  int tid  = blockIdx.x*256 + threadIdx.x;
  int wave = tid >> 6;
  int l    = tid & 63;
  int qg = wave & 127;       // 0..127
  int pg = wave >> 7;        // 0..8
  int q0 = qg * 8, pr0 = pg * 8;

  float acc[8][8];
  #pragma unroll
  for (int j = 0; j < 8; j++)
    #pragma unroll
    for (int i = 0; i < 8; i++) acc[j][i] = 0.f;

  for (int p = 0; p < PP; p++){
    float qr[8], vr[8];
    #pragma unroll
    for (int j = 0; j < 8; j++){
      int q = q0 + j;
      qr[j] = feat[(size_t)(NS + q)*6400 + l*100 + p] * invq[q*100 + p];
    }
    #pragma unroll
    for (int i = 0; i < 8; i++){
      int pr = pr0 + i; if (pr >= NPAIR) pr = 0;
      vr[i] = vpt[(size_t)pr*6400 + p*64 + l];
    }
    #pragma unroll
    for (int j = 0; j < 8; j++)
      #pragma unroll
      for (int i = 0; i < 8; i++)
        acc[j][i] += qr[j] * vr[i];
  }
  #pragma unroll
  for (int j = 0; j < 8; j++)
    #pragma unroll
    for (int i = 0; i < 8; i++){
      float s = redsum64(acc[j][i]);
      if (l == 0 && (pr0 + i) < NPAIR)
        sim[(q0 + j)*NPAIR + pr0 + i] = s;
    }
}

// ---------------- kernel M: per-(q,n) softmax over 14 views -> p_w ----------------
__global__ __launch_bounds__(256) void kM(const float* __restrict__ sim,
                                          const float* __restrict__ vninv,
                                          const float* __restrict__ temp,
                                          float* __restrict__ pw){
  int t = blockIdx.x*256 + threadIdx.x;
  if (t >= NQ*NWAY) return;
  int q = t / NWAY, n = t - q*NWAY;
  float invT = 1.f / (temp[0] + 1e-6f);
  float s[PRJ];
  float m = -3.4e38f;
  #pragma unroll
  for (int v = 0; v < PRJ; v++){
    int pr = n*PRJ + v;
    s[v] = sim[q*NPAIR + pr] * vninv[pr] * invT;
    m = fmaxf(m, s[v]);
  }
  float sum = 0.f;
  #pragma unroll
  for (int v = 0; v < PRJ; v++){ s[v] = expf(s[v] - m); sum += s[v]; }
  float rs = 1.f / sum;
  #pragma unroll
  for (int v = 0; v < PRJ; v++) pw[q*NPAIR + n*PRJ + v] = s[v] * rs;
}

// ---------------- kernel P: proto_q[q][n][d] with spatial sigmoid attention ----------------
__global__ __launch_bounds__(256) void kP(const float* __restrict__ vpt,
                                          const float* __restrict__ pw,
                                          float* __restrict__ pq){
  int tid  = blockIdx.x*256 + threadIdx.x;
  int wave = tid >> 6;        // 0..1279
  int l    = tid & 63;
  int n  = wave >> 8;         // 0..4
  int q0 = (wave & 255) * 4;  // 4 queries per wave

  float w[4][PRJ];
  #pragma unroll
  for (int j = 0; j < 4; j++)
    #pragma unroll
    for (int v = 0; v < PRJ; v++)
      w[j][v] = pw[(q0 + j)*NPAIR + n*PRJ + v];

  float acc[4] = {0.f, 0.f, 0.f, 0.f};
  const float* vb = vpt + (size_t)n * PRJ * 6400;
  for (int p = 0; p < PP; p++){
    float vv[PRJ];
    #pragma unroll
    for (int v = 0; v < PRJ; v++) vv[v] = vb[v*6400 + p*64 + l];
    #pragma unroll
    for (int j = 0; j < 4; j++){
      float val = 0.f;
      #pragma unroll
      for (int v = 0; v < PRJ; v++) val += w[j][v] * vv[v];
      float m = redsum64(val) * (1.f/64.f);
      float sg = 1.f / (1.f + expf(-m));
      acc[j] += sg * val;
    }
  }
  #pragma unroll
  for (int j = 0; j < 4; j++)
    pq[((q0 + j)*NWAY + n)*64 + l] = acc[j];
}

// ---------------- kernel F: per-query epilogue (cos/QSA/DeltaGate/pred/losses) ----------------
__global__ __launch_bounds__(64) void kF(const float* __restrict__ qv,
                                         const float* __restrict__ pqw,
                                         const float* __restrict__ base,
                                         const float* __restrict__ Wq,
                                         const float* __restrict__ bq,
                                         const float* __restrict__ Wk,
                                         const float* __restrict__ bk,
                                         const float* __restrict__ gate,
                                         const int*   __restrict__ label,
                                         float* __restrict__ pred,
                                         float* __restrict__ cls,
                                         float* __restrict__ aln){
  __shared__ float qvl[64];
  __shared__ float qp[16];
  __shared__ float dl[64];
  int q = blockIdx.x, l = threadIdx.x;

  float qvv = qv[q*64 + l];
  qvl[l] = qvv;
  __syncthreads();
  float qss = redsum64(qvv*qvv);
  float qn8 = fmaxf(sqrtf(qss), 1e-8f);

  if (l < 16){
    float s = bq[l];
    #pragma unroll
    for (int d = 0; d < 64; d++) s += qvl[d] * Wq[d*16 + l];
    qp[l] = s;
  }
  __syncthreads();

  float wkq = 0.f;
  #pragma unroll
  for (int e = 0; e < 16; e++) wkq += Wk[l*16 + e] * qp[e];
  float qpb = 0.f;
  #pragma unroll
  for (int e = 0; e < 16; e++) qpb += qp[e] * bk[e];

  float pqv[NWAY], cosv[NWAY], sc[NWAY];
  #pragma unroll
  for (int n = 0; n < NWAY; n++){
    float x = pqw[(q*NWAY + n)*64 + l];
    pqv[n] = x;
    float dq = redsum64(qvv * x);
    float ps = redsum64(x * x);
    cosv[n] = dq / (qn8 * fmaxf(sqrtf(ps), 1e-8f));
    float sd = redsum64(x * wkq);
    sc[n] = (sd + qpb) * 0.25f;     // / sqrt(16)
  }

  // attn softmax over n
  float am = sc[0];
  #pragma unroll
  for (int n = 1; n < NWAY; n++) am = fmaxf(am, sc[n]);
  float ae[NWAY], asum = 0.f;
  #pragma unroll
  for (int n = 0; n < NWAY; n++){ ae[n] = expf(sc[n] - am); asum += ae[n]; }
  float rasum = 1.f / asum;

  // gate band weights
  float g0 = gate[0], g1 = gate[1], g2 = gate[2];
  float gm = fmaxf(fmaxf(g0, g1), g2);
  float e0 = expf(g0 - gm), e1 = expf(g1 - gm), e2 = expf(g2 - gm);
  float gs = 1.f / (e0 + e1 + e2);
  float b0 = (e0 + e1 + e2) * gs;   // rank <16
  float b1 = (e1 + e2) * gs;        // rank <32
  float b2 = e2 * gs;               // rank <48

  float cos2[NWAY];
  #pragma unroll
  for (int n = 0; n < NWAY; n++){
    float f  = pqv[n] * (ae[n] * rasum);
    float dd = fabsf(f - base[n*64 + l]);
    dl[l] = dd;
    __syncthreads();
    int rank = 0;
    #pragma unroll 8
    for (int j = 0; j < 64; j++){
      float dj = dl[j];
      rank += (dj > dd) || (dj == dd && j < l);
    }
    __syncthreads();
    float cw = (rank < 16) ? b0 : (rank < 32) ? b1 : (rank < 48) ? b2 : 0.f;
    float gl = f * cw;
    float gss = redsum64(gl * gl);
    float num = redsum64(qvv * gl);
    cos2[n] = num / (qn8 * fmaxf(sqrtf(gss), 1e-12f));
  }

  // pred softmax
  float mx = cos2[0];
  #pragma unroll
  for (int n = 1; n < NWAY; n++) mx = fmaxf(mx, cos2[n]);
  float pe[NWAY], psum = 0.f;
  #pragma unroll
  for (int n = 0; n < NWAY; n++){ pe[n] = expf(cos2[n] - mx); psum += pe[n]; }
  float rp = 1.f / psum;
  if (l == 0){
    #pragma unroll
    for (int n = 0; n < NWAY; n++) pred[q*NWAY + n] = pe[n] * rp;
  }

  // cls loss: lse(32*cos2) - 32*cos2[label]
  int lab = label[q];
  float lm = LAMDA * mx;
  float lsum = 0.f;
  #pragma unroll
  for (int n = 0; n < NWAY; n++) lsum += expf(LAMDA * cos2[n] - lm);
  float c2l = cos2[0], cosl = cosv[0];
  #pragma unroll
  for (int n = 1; n < NWAY; n++){
    if (lab == n){ c2l = cos2[n]; cosl = cosv[n]; }
  }
  float clsv = (lm + logf(lsum)) - LAMDA * c2l;

  // align loss
  float sum5 = 0.f, minn = 3.4e38f;
  #pragma unroll
  for (int n = 0; n < NWAY; n++){
    sum5 += cosv[n];
    if (n != lab) minn = fminf(minn, cosv[n]);
  }
  float hn = (sum5 - cosl - minn) * (1.f/3.f);
  float al = fmaxf(hn - cosl + MARGIN, 0.f);
  if (l == 0){ cls[q] = clsv; aln[q] = al; }
}

// ---------------- kernel L: deterministic loss reduction ----------------
__global__ __launch_bounds__(256) void kL(const float* __restrict__ cls,
                                          const float* __restrict__ aln,
                                          float* __restrict__ out){
  __shared__ float r1[256], r2[256];
  int t = threadIdx.x;
  float s1 = 0.f, s2 = 0.f;
  for (int i = t; i < NQ; i += 256){ s1 += cls[i]; s2 += aln[i]; }
  r1[t] = s1; r2[t] = s2;
  __syncthreads();
  for (int o = 128; o > 0; o >>= 1){
    if (t < o){ r1[t] += r1[t + o]; r2[t] += r2[t + o]; }
    __syncthreads();
  }
  if (t == 0)
    out[NQ*NWAY] = r1[0]*(1.f/NQ) + 0.3f*(r2[0]*(1.f/NQ));
}

extern "C" void kernel_launch(void* const* d_in, const int* in_sizes, int n_in,
                              void* d_out, int out_size, void* d_ws, size_t ws_size,
                              hipStream_t stream){
  const float* feat = (const float*)d_in[0];
  const float* temp = (const float*)d_in[1];
  const float* gate = (const float*)d_in[2];
  const float* Wq   = (const float*)d_in[3];
  const float* bq   = (const float*)d_in[4];
  const float* Wk   = (const float*)d_in[5];
  const float* bk   = (const float*)d_in[6];
  const int*   lab  = (const int*)d_in[7];
  float* out = (float*)d_out;
  float* ws  = (float*)d_ws;

  float* vpt   = ws + VPT_OFF;
  float* vninv = ws + VNINV_OFF;
  float* base  = ws + BASE_OFF;
  float* qv    = ws + QV_OFF;
  float* invq  = ws + INVQ_OFF;
  float* sim   = ws + SIM_OFF;
  float* pw    = ws + PW_OFF;
  float* pq    = ws + PQ_OFF;
  float* cls   = ws + CLS_OFF;
  float* aln   = ws + ALN_OFF;

  hipLaunchKernelGGL(kV, dim3(NPAIR), dim3(256), 0, stream, feat, vpt, vninv);
  hipLaunchKernelGGL(kB, dim3(NWAY), dim3(64), 0, stream, vpt, base);
  hipLaunchKernelGGL(kQ, dim3(NQ), dim3(256), 0, stream, feat, invq, qv);
  hipLaunchKernelGGL(kS, dim3(288), dim3(256), 0, stream, feat, invq, vpt, sim);
  hipLaunchKernelGGL(kM, dim3((NQ*NWAY + 255)/256), dim3(256), 0, stream, sim, vninv, temp, pw);
  hipLaunchKernelGGL(kP, dim3(320), dim3(256), 0, stream, vpt, pw, pq);
  hipLaunchKernelGGL(kF, dim3(NQ), dim3(64), 0, stream, qv, pq, base, Wq, bq, Wk, bk, gate, lab, out, cls, aln);
  hipLaunchKernelGGL(kL, dim3(1), dim3(256), 0, stream, cls, aln, out);
}

// Round 2
// 268.905 us; speedup vs baseline: 1.9202x; 1.9202x over previous
//
#include <hip/hip_runtime.h>
#include <math.h>

#define NWAY 5
#define KSHOT 5
#define PRJ 14
#define DD 64
#define PP 100
#define NQ 1024
#define NS 350
#define NPAIR 70
#define LAMDA 32.0f
#define MARGIN 0.3f

// ---- workspace layout (floats), total ~8.23 MB ----
#define VPT_OFF   0          // [70][100][64]  = 448000   (p-major,d inner)
#define VPTT_OFF  448000     // [70][6400]     = 448000   (f = d*100+p contiguous)
#define MM_OFF    896000     // [70][100]      = 7000     (mean over d)
#define VNINV_OFF 903000     // [70] pad 128
#define BASE_OFF  903128     // [5][64]
#define QV_OFF    903448     // [1024][64]
#define INVQ_OFF  968984     // [1024][100]
#define SIM_OFF   1071384    // [1024][70]
#define PW_OFF    1143064    // [1024][70]
#define SG_OFF    1214744    // [1024][5][100] = 512000
#define PQ_OFF    1726744    // [1024][5][64]  = 327680
#define CLS_OFF   2054424    // [1024]
#define ALN_OFF   2055448    // [1024]

__device__ __forceinline__ float redsum64(float x){
  #pragma unroll
  for (int o = 1; o < 64; o <<= 1) x += __shfl_xor(x, o, 64);
  return x;
}

// ---------------- kV: support normalize + vpt + vptT + M + vninv ----------------
__global__ __launch_bounds__(256) void kV(const float* __restrict__ feat,
                                          float* __restrict__ vpt,
                                          float* __restrict__ vptT,
                                          float* __restrict__ MM,
                                          float* __restrict__ vninv){
  __shared__ float lds[64*101];
  __shared__ float inv[100];
  __shared__ float red[4];
  int pair = blockIdx.x;
  int n = pair / PRJ, v = pair - n*PRJ;
  int t = threadIdx.x;
  float acc[25];
  #pragma unroll
  for (int i = 0; i < 25; i++) acc[i] = 0.f;

  for (int k = 0; k < KSHOT; k++){
    int s = (n*KSHOT + k)*PRJ + v;
    const float* fp = feat + (size_t)s * 6400;
    #pragma unroll
    for (int i = 0; i < 25; i++){
      int j = t + 256*i;
      int d = j / 100, p = j - d*100;
      lds[d*101 + p] = fp[j];
    }
    __syncthreads();
    if (t < 100){
      float ss = 0.f;
      #pragma unroll
      for (int d = 0; d < 64; d++){ float x = lds[d*101 + t]; ss += x*x; }
      inv[t] = 1.f / fmaxf(sqrtf(ss), 1e-12f);
    }
    __syncthreads();
    #pragma unroll
    for (int i = 0; i < 25; i++){
      int j = t + 256*i;
      int p = j >> 6, d = j & 63;
      acc[i] += lds[d*101 + p] * inv[p];
    }
    __syncthreads();
  }
  // write vpt [p][d], stash normalized mean into lds [d][p] for transpose
  float ssq = 0.f;
  #pragma unroll
  for (int i = 0; i < 25; i++){
    int j = t + 256*i;
    int p = j >> 6, d = j & 63;
    float val = acc[i] * 0.2f;
    vpt[(size_t)pair*6400 + j] = val;
    lds[d*101 + p] = val;
    ssq += val*val;
  }
  ssq = redsum64(ssq);
  if ((t & 63) == 0) red[t >> 6] = ssq;
  __syncthreads();
  if (t == 0){
    float tot = red[0] + red[1] + red[2] + red[3];
    vninv[pair] = 1.f / fmaxf(sqrtf(tot), 1e-12f);
  }
  // coalesced vptT write: f = d*100+p -> lds[f + f/100]
  #pragma unroll
  for (int i = 0; i < 25; i++){
    int f = t + 256*i;
    int d = f / 100;
    vptT[(size_t)pair*6400 + f] = lds[f + d];
  }
  // M[pair][p] = mean over d
  if (t < 100){
    float s = 0.f;
    #pragma unroll
    for (int d = 0; d < 64; d++) s += lds[d*101 + t];
    MM[pair*100 + t] = s * (1.f/64.f);
  }
}

// ---------------- kB: base[n][d] ----------------
__global__ __launch_bounds__(256) void kB(const float* __restrict__ vpt,
                                          float* __restrict__ base){
  __shared__ float r[256];
  int n = blockIdx.x, t = threadIdx.x;
  int d = t & 63, g = t >> 6;
  float s = 0.f;
  for (int i = g; i < 1400; i += 4)
    s += vpt[((size_t)n*1400 + i)*64 + d];
  r[t] = s;
  __syncthreads();
  if (g == 0)
    base[n*64 + d] = (r[d] + r[64+d] + r[128+d] + r[192+d]) * (1.f/1400.f);
}

// ---------------- kQ: per-query inv norms + query_vec ----------------
__global__ __launch_bounds__(256) void kQ(const float* __restrict__ feat,
                                          float* __restrict__ invq,
                                          float* __restrict__ qv){
  __shared__ float lds[64*101];
  __shared__ float inv[100];
  int q = blockIdx.x, t = threadIdx.x;
  const float* fp = feat + (size_t)(NS + q) * 6400;
  #pragma unroll
  for (int i = 0; i < 25; i++){
    int j = t + 256*i;
    int d = j / 100, p = j - d*100;
    lds[d*101 + p] = fp[j];
  }
  __syncthreads();
  if (t < 100){
    float ss = 0.f;
    #pragma unroll
    for (int d = 0; d < 64; d++){ float x = lds[d*101 + t]; ss += x*x; }
    float iv = 1.f / fmaxf(sqrtf(ss), 1e-12f);
    inv[t] = iv;
    invq[q*100 + t] = iv;
  }
  __syncthreads();
  if (t < 64){
    float s = 0.f;
    for (int p = 0; p < PP; p++) s += lds[t*101 + p] * inv[p];
    qv[q*64 + t] = s * 0.01f;
  }
}

// ---------------- kS v2: sim = qn x vptT, LDS-staged A, coalesced B ----------------
// grid 256: block = 8 queries x 35 pairs (half), 4 waves: pairs 9/9/9/8
__global__ __launch_bounds__(256) void kS(const float* __restrict__ feat,
                                          const float* __restrict__ invq,
                                          const float* __restrict__ vptT,
                                          float* __restrict__ sim){
  __shared__ float A[8*1280];
  __shared__ float inv_l[800];
  int b = blockIdx.x;
  int qg = b >> 1, ph = b & 1;
  int q0 = qg * 8;
  int t = threadIdx.x;
  int w = t >> 6, l = t & 63;

  for (int i = t; i < 800; i += 256) inv_l[i] = invq[q0*100 + i];

  int npr = (w < 3) ? 9 : 8;
  int prs = ph*35 + w*9;

  float acc[8][9];
  #pragma unroll
  for (int q = 0; q < 8; q++)
    #pragma unroll
    for (int j = 0; j < 9; j++) acc[q][j] = 0.f;

  const float4* fq4 = (const float4*)(feat + (size_t)NS*6400);
  const float4* B4  = (const float4*)vptT;
  float4* A4 = (float4*)A;

  for (int c = 0; c < 5; c++){
    __syncthreads();
    int f0 = c * 1280;
    #pragma unroll
    for (int i = 0; i < 10; i++){
      int fi = i*256 + t;           // 0..2559
      int q  = fi / 320, c4 = fi - q*320;
      float4 vv = fq4[(size_t)(q0+q)*1600 + (f0>>2) + c4];
      int fb = f0 + c4*4;
      float r0 = vv.x, r1 = vv.y, r2 = vv.z, r3 = vv.w;
      int p0 = fb % 100;
      int p1 = (fb+1) % 100;
      int p2 = (fb+2) % 100;
      int p3 = (fb+3) % 100;
      r0 *= inv_l[q*100 + p0];
      r1 *= inv_l[q*100 + p1];
      r2 *= inv_l[q*100 + p2];
      r3 *= inv_l[q*100 + p3];
      A4[q*320 + c4] = make_float4(r0, r1, r2, r3);
    }
    __syncthreads();
    for (int s = 0; s < 5; s++){
      float4 a4[8];
      #pragma unroll
      for (int q = 0; q < 8; q++) a4[q] = A4[q*320 + s*64 + l];
      #pragma unroll
      for (int j = 0; j < 9; j++){
        if (j < npr){
          float4 b4 = B4[(size_t)(prs+j)*1600 + (f0>>2) + s*64 + l];
          #pragma unroll
          for (int q = 0; q < 8; q++)
            acc[q][j] += a4[q].x*b4.x + a4[q].y*b4.y + a4[q].z*b4.z + a4[q].w*b4.w;
        }
      }
    }
  }
  #pragma unroll
  for (int q = 0; q < 8; q++)
    #pragma unroll
    for (int j = 0; j < 9; j++){
      if (j < npr){
        float s = redsum64(acc[q][j]);
        if (l == 0) sim[(q0+q)*NPAIR + prs + j] = s;
      }
    }
}

// ---------------- kM: per-(q,n) softmax over 14 views ----------------
__global__ __launch_bounds__(256) void kM(const float* __restrict__ sim,
                                          const float* __restrict__ vninv,
                                          const float* __restrict__ temp,
                                          float* __restrict__ pw){
  int t = blockIdx.x*256 + threadIdx.x;
  if (t >= NQ*NWAY) return;
  int q = t / NWAY, n = t - q*NWAY;
  float invT = 1.f / (temp[0] + 1e-6f);
  float s[PRJ];
  float m = -3.4e38f;
  #pragma unroll
  for (int v = 0; v < PRJ; v++){
    int pr = n*PRJ + v;
    s[v] = sim[q*NPAIR + pr] * vninv[pr] * invT;
    m = fmaxf(m, s[v]);
  }
  float sum = 0.f;
  #pragma unroll
  for (int v = 0; v < PRJ; v++){ s[v] = expf(s[v] - m); sum += s[v]; }
  float rs = 1.f / sum;
  #pragma unroll
  for (int v = 0; v < PRJ; v++) pw[q*NPAIR + n*PRJ + v] = s[v] * rs;
}

// ---------------- kSg: sg[q][n][p] = sigmoid(sum_v pw*M) ----------------
__global__ __launch_bounds__(512) void kSg(const float* __restrict__ pw,
                                           const float* __restrict__ MM,
                                           float* __restrict__ sg){
  int q = blockIdx.x, t = threadIdx.x;
  if (t >= 500) return;
  int n = t / 100, p = t - n*100;
  float s = 0.f;
  #pragma unroll
  for (int v = 0; v < PRJ; v++)
    s += pw[q*NPAIR + n*PRJ + v] * MM[(n*PRJ + v)*100 + p];
  sg[(size_t)q*500 + t] = 1.f / (1.f + expf(-s));
}

// ---------------- kP v2: proto_q via precomputed sg, no cross-lane chains ----------------
// grid 320: block b: n = b/64, 4 waves = 16 consecutive queries (same n -> L1 reuse)
__global__ __launch_bounds__(256) void kP(const float* __restrict__ vpt,
                                          const float* __restrict__ pw,
                                          const float* __restrict__ sg,
                                          float* __restrict__ pq){
  int b = blockIdx.x;
  int n = b >> 6;
  int qb = b & 63;
  int t = threadIdx.x, w = t >> 6, l = t & 63;
  int q0 = qb*16 + w*4;

  float wq[4][PRJ];
  #pragma unroll
  for (int j = 0; j < 4; j++)
    #pragma unroll
    for (int v = 0; v < PRJ; v++)
      wq[j][v] = pw[(q0+j)*NPAIR + n*PRJ + v];

  float acc[4] = {0.f, 0.f, 0.f, 0.f};
  const float* vb = vpt + (size_t)n * PRJ * 6400;
  for (int p = 0; p < PP; p++){
    float vv[PRJ];
    #pragma unroll
    for (int v = 0; v < PRJ; v++) vv[v] = vb[v*6400 + p*64 + l];
    #pragma unroll
    for (int j = 0; j < 4; j++){
      float dot = 0.f;
      #pragma unroll
      for (int v = 0; v < PRJ; v++) dot += wq[j][v] * vv[v];
      float sgv = sg[(size_t)(q0+j)*500 + n*100 + p];
      acc[j] += sgv * dot;
    }
  }
  #pragma unroll
  for (int j = 0; j < 4; j++)
    pq[((q0+j)*NWAY + n)*64 + l] = acc[j];
}

// ---------------- kF: per-query epilogue ----------------
__global__ __launch_bounds__(64) void kF(const float* __restrict__ qv,
                                         const float* __restrict__ pqw,
                                         const float* __restrict__ base,
                                         const float* __restrict__ Wq,
                                         const float* __restrict__ bq,
                                         const float* __restrict__ Wk,
                                         const float* __restrict__ bk,
                                         const float* __restrict__ gate,
                                         const int*   __restrict__ label,
                                         float* __restrict__ pred,
                                         float* __restrict__ cls,
                                         float* __restrict__ aln){
  __shared__ float qvl[64];
  __shared__ float qp[16];
  __shared__ float dl[64];
  int q = blockIdx.x, l = threadIdx.x;

  float qvv = qv[q*64 + l];
  qvl[l] = qvv;
  __syncthreads();
  float qss = redsum64(qvv*qvv);
  float qn8 = fmaxf(sqrtf(qss), 1e-8f);

  if (l < 16){
    float s = bq[l];
    #pragma unroll
    for (int d = 0; d < 64; d++) s += qvl[d] * Wq[d*16 + l];
    qp[l] = s;
  }
  __syncthreads();

  float wkq = 0.f;
  #pragma unroll
  for (int e = 0; e < 16; e++) wkq += Wk[l*16 + e] * qp[e];
  float qpb = 0.f;
  #pragma unroll
  for (int e = 0; e < 16; e++) qpb += qp[e] * bk[e];

  float pqv[NWAY], cosv[NWAY], sc[NWAY];
  #pragma unroll
  for (int n = 0; n < NWAY; n++){
    float x = pqw[(q*NWAY + n)*64 + l];
    pqv[n] = x;
    float dq = redsum64(qvv * x);
    float ps = redsum64(x * x);
    cosv[n] = dq / (qn8 * fmaxf(sqrtf(ps), 1e-8f));
    float sd = redsum64(x * wkq);
    sc[n] = (sd + qpb) * 0.25f;
  }

  float am = sc[0];
  #pragma unroll
  for (int n = 1; n < NWAY; n++) am = fmaxf(am, sc[n]);
  float ae[NWAY], asum = 0.f;
  #pragma unroll
  for (int n = 0; n < NWAY; n++){ ae[n] = expf(sc[n] - am); asum += ae[n]; }
  float rasum = 1.f / asum;

  float g0 = gate[0], g1 = gate[1], g2 = gate[2];
  float gm = fmaxf(fmaxf(g0, g1), g2);
  float e0 = expf(g0 - gm), e1 = expf(g1 - gm), e2 = expf(g2 - gm);
  float gs = 1.f / (e0 + e1 + e2);
  float b0 = (e0 + e1 + e2) * gs;
  float b1 = (e1 + e2) * gs;
  float b2 = e2 * gs;

  float cos2[NWAY];
  #pragma unroll
  for (int n = 0; n < NWAY; n++){
    float f  = pqv[n] * (ae[n] * rasum);
    float dd = fabsf(f - base[n*64 + l]);
    dl[l] = dd;
    __syncthreads();
    int rank = 0;
    #pragma unroll 8
    for (int j = 0; j < 64; j++){
      float dj = dl[j];
      rank += (dj > dd) || (dj == dd && j < l);
    }
    __syncthreads();
    float cw = (rank < 16) ? b0 : (rank < 32) ? b1 : (rank < 48) ? b2 : 0.f;
    float gl = f * cw;
    float gss = redsum64(gl * gl);
    float num = redsum64(qvv * gl);
    cos2[n] = num / (qn8 * fmaxf(sqrtf(gss), 1e-12f));
  }

  float mx = cos2[0];
  #pragma unroll
  for (int n = 1; n < NWAY; n++) mx = fmaxf(mx, cos2[n]);
  float pe[NWAY], psum = 0.f;
  #pragma unroll
  for (int n = 0; n < NWAY; n++){ pe[n] = expf(cos2[n] - mx); psum += pe[n]; }
  float rp = 1.f / psum;
  if (l == 0){
    #pragma unroll
    for (int n = 0; n < NWAY; n++) pred[q*NWAY + n] = pe[n] * rp;
  }

  int lab = label[q];
  float lm = LAMDA * mx;
  float lsum = 0.f;
  #pragma unroll
  for (int n = 0; n < NWAY; n++) lsum += expf(LAMDA * cos2[n] - lm);
  float c2l = cos2[0], cosl = cosv[0];
  #pragma unroll
  for (int n = 1; n < NWAY; n++){
    if (lab == n){ c2l = cos2[n]; cosl = cosv[n]; }
  }
  float clsv = (lm + logf(lsum)) - LAMDA * c2l;

  float sum5 = 0.f, minn = 3.4e38f;
  #pragma unroll
  for (int n = 0; n < NWAY; n++){
    sum5 += cosv[n];
    if (n != lab) minn = fminf(minn, cosv[n]);
  }
  float hn = (sum5 - cosl - minn) * (1.f/3.f);
  float al = fmaxf(hn - cosl + MARGIN, 0.f);
  if (l == 0){ cls[q] = clsv; aln[q] = al; }
}

// ---------------- kL: loss reduction ----------------
__global__ __launch_bounds__(256) void kL(const float* __restrict__ cls,
                                          const float* __restrict__ aln,
                                          float* __restrict__ out){
  __shared__ float r1[256], r2[256];
  int t = threadIdx.x;
  float s1 = 0.f, s2 = 0.f;
  for (int i = t; i < NQ; i += 256){ s1 += cls[i]; s2 += aln[i]; }
  r1[t] = s1; r2[t] = s2;
  __syncthreads();
  for (int o = 128; o > 0; o >>= 1){
    if (t < o){ r1[t] += r1[t + o]; r2[t] += r2[t + o]; }
    __syncthreads();
  }
  if (t == 0)
    out[NQ*NWAY] = r1[0]*(1.f/NQ) + 0.3f*(r2[0]*(1.f/NQ));
}

extern "C" void kernel_launch(void* const* d_in, const int* in_sizes, int n_in,
                              void* d_out, int out_size, void* d_ws, size_t ws_size,
                              hipStream_t stream){
  const float* feat = (const float*)d_in[0];
  const float* temp = (const float*)d_in[1];
  const float* gate = (const float*)d_in[2];
  const float* Wq   = (const float*)d_in[3];
  const float* bq   = (const float*)d_in[4];
  const float* Wk   = (const float*)d_in[5];
  const float* bk   = (const float*)d_in[6];
  const int*   lab  = (const int*)d_in[7];
  float* out = (float*)d_out;
  float* ws  = (float*)d_ws;

  float* vpt   = ws + VPT_OFF;
  float* vptT  = ws + VPTT_OFF;
  float* MMp   = ws + MM_OFF;
  float* vninv = ws + VNINV_OFF;
  float* base  = ws + BASE_OFF;
  float* qv    = ws + QV_OFF;
  float* invq  = ws + INVQ_OFF;
  float* sim   = ws + SIM_OFF;
  float* pw    = ws + PW_OFF;
  float* sg    = ws + SG_OFF;
  float* pq    = ws + PQ_OFF;
  float* cls   = ws + CLS_OFF;
  float* aln   = ws + ALN_OFF;

  hipLaunchKernelGGL(kV, dim3(NPAIR), dim3(256), 0, stream, feat, vpt, vptT, MMp, vninv);
  hipLaunchKernelGGL(kB, dim3(NWAY), dim3(256), 0, stream, vpt, base);
  hipLaunchKernelGGL(kQ, dim3(NQ), dim3(256), 0, stream, feat, invq, qv);
  hipLaunchKernelGGL(kS, dim3(256), dim3(256), 0, stream, feat, invq, vptT, sim);
  hipLaunchKernelGGL(kM, dim3((NQ*NWAY + 255)/256), dim3(256), 0, stream, sim, vninv, temp, pw);
  hipLaunchKernelGGL(kSg, dim3(NQ), dim3(512), 0, stream, pw, MMp, sg);
  hipLaunchKernelGGL(kP, dim3(320), dim3(256), 0, stream, vpt, pw, sg, pq);
  hipLaunchKernelGGL(kF, dim3(NQ), dim3(64), 0, stream, qv, pq, base, Wq, bq, Wk, bk, gate, lab, out, cls, aln);
  hipLaunchKernelGGL(kL, dim3(1), dim3(256), 0, stream, cls, aln, out);
}

// Round 3
// 191.923 us; speedup vs baseline: 2.6904x; 1.4011x over previous
//
#include <hip/hip_runtime.h>
#include <math.h>

#define NWAY 5
#define KSHOT 5
#define PRJ 14
#define DD 64
#define PP 100
#define NQ 1024
#define NS 350
#define NPAIR 70
#define LAMDA 32.0f
#define MARGIN 0.3f

// ---- workspace layout (floats) ----
#define VPT_OFF   0          // [70][100][64]  = 448000   (p-major,d inner)
#define VPTT_OFF  448000     // [70][6400]     = 448000   (f = d*100+p contiguous)
#define MM_OFF    896000     // [70][100]      = 7000     (mean over d)
#define VNINV_OFF 903000     // [70] pad 128
#define PSUM_OFF  903128     // [70][64] = 4480
#define BASE_OFF  907608     // [5][64]
#define QV_OFF    907928     // [1024][64]
#define INVQ_OFF  973464     // [1024][100]
#define SIM_OFF   1075864    // [1024][70]
#define PW_OFF    1147544    // [1024][70]
#define SG_OFF    1219224    // [1024][5][100] = 512000
#define PQ_OFF    1731224    // [1024][5][64]  = 327680
#define CLS_OFF   2058904    // [1024]
#define ALN_OFF   2059928    // [1024]

__device__ __forceinline__ float redsum64(float x){
  #pragma unroll
  for (int o = 1; o < 64; o <<= 1) x += __shfl_xor(x, o, 64);
  return x;
}

// ---------------- kV: support normalize + vpt + vptT + M + vninv + psum ----------------
__global__ __launch_bounds__(256) void kV(const float* __restrict__ feat,
                                          float* __restrict__ vpt,
                                          float* __restrict__ vptT,
                                          float* __restrict__ MM,
                                          float* __restrict__ vninv,
                                          float* __restrict__ psum){
  __shared__ float lds[64*101];
  __shared__ float inv[100];
  __shared__ float red[4];
  int pair = blockIdx.x;
  int n = pair / PRJ, v = pair - n*PRJ;
  int t = threadIdx.x;
  float acc[25];
  #pragma unroll
  for (int i = 0; i < 25; i++) acc[i] = 0.f;

  for (int k = 0; k < KSHOT; k++){
    int s = (n*KSHOT + k)*PRJ + v;
    const float* fp = feat + (size_t)s * 6400;
    #pragma unroll
    for (int i = 0; i < 25; i++){
      int j = t + 256*i;
      int d = j / 100, p = j - d*100;
      lds[d*101 + p] = fp[j];
    }
    __syncthreads();
    if (t < 100){
      float ss = 0.f;
      #pragma unroll
      for (int d = 0; d < 64; d++){ float x = lds[d*101 + t]; ss += x*x; }
      inv[t] = 1.f / fmaxf(sqrtf(ss), 1e-12f);
    }
    __syncthreads();
    #pragma unroll
    for (int i = 0; i < 25; i++){
      int j = t + 256*i;
      int p = j >> 6, d = j & 63;
      acc[i] += lds[d*101 + p] * inv[p];
    }
    __syncthreads();
  }
  // write vpt [p][d], stash normalized mean into lds [d][p] for transpose
  float ssq = 0.f;
  #pragma unroll
  for (int i = 0; i < 25; i++){
    int j = t + 256*i;
    int p = j >> 6, d = j & 63;
    float val = acc[i] * 0.2f;
    vpt[(size_t)pair*6400 + j] = val;
    lds[d*101 + p] = val;
    ssq += val*val;
  }
  ssq = redsum64(ssq);
  if ((t & 63) == 0) red[t >> 6] = ssq;
  __syncthreads();
  if (t == 0){
    float tot = red[0] + red[1] + red[2] + red[3];
    vninv[pair] = 1.f / fmaxf(sqrtf(tot), 1e-12f);
  }
  // coalesced vptT write: f = d*100+p -> lds[f + f/100]
  #pragma unroll
  for (int i = 0; i < 25; i++){
    int f = t + 256*i;
    int d = f / 100;
    vptT[(size_t)pair*6400 + f] = lds[f + d];
  }
  // M[pair][p] = mean over d; psum[pair][d] = sum over p
  if (t < 100){
    float s = 0.f;
    #pragma unroll
    for (int d = 0; d < 64; d++) s += lds[d*101 + t];
    MM[pair*100 + t] = s * (1.f/64.f);
  }
  if (t >= 128 && t < 192){
    int d = t - 128;
    float s = 0.f;
    #pragma unroll
    for (int p = 0; p < PP; p++) s += lds[d*101 + p];
    psum[pair*64 + d] = s;
  }
}

// ---------------- kB v2: tiny reduce of psum -> base ----------------
__global__ __launch_bounds__(320) void kB(const float* __restrict__ psum,
                                          float* __restrict__ base){
  int t = threadIdx.x;           // 0..319
  int n = t >> 6, d = t & 63;
  float s = 0.f;
  #pragma unroll
  for (int v = 0; v < PRJ; v++) s += psum[(n*PRJ + v)*64 + d];
  base[t] = s * (1.f/1400.f);
}

// ---------------- kQ: per-query inv norms + query_vec ----------------
__global__ __launch_bounds__(256) void kQ(const float* __restrict__ feat,
                                          float* __restrict__ invq,
                                          float* __restrict__ qv){
  __shared__ float lds[64*101];
  __shared__ float inv[100];
  int q = blockIdx.x, t = threadIdx.x;
  const float* fp = feat + (size_t)(NS + q) * 6400;
  #pragma unroll
  for (int i = 0; i < 25; i++){
    int j = t + 256*i;
    int d = j / 100, p = j - d*100;
    lds[d*101 + p] = fp[j];
  }
  __syncthreads();
  if (t < 100){
    float ss = 0.f;
    #pragma unroll
    for (int d = 0; d < 64; d++){ float x = lds[d*101 + t]; ss += x*x; }
    float iv = 1.f / fmaxf(sqrtf(ss), 1e-12f);
    inv[t] = iv;
    invq[q*100 + t] = iv;
  }
  __syncthreads();
  if (t < 64){
    float s = 0.f;
    for (int p = 0; p < PP; p++) s += lds[t*101 + p] * inv[p];
    qv[q*64 + t] = s * 0.01f;
  }
}

// ---------------- kS: sim = qn x vptT, LDS-staged A, coalesced B ----------------
__global__ __launch_bounds__(256) void kS(const float* __restrict__ feat,
                                          const float* __restrict__ invq,
                                          const float* __restrict__ vptT,
                                          float* __restrict__ sim){
  __shared__ float A[8*1280];
  __shared__ float inv_l[800];
  int b = blockIdx.x;
  int qg = b >> 1, ph = b & 1;
  int q0 = qg * 8;
  int t = threadIdx.x;
  int w = t >> 6, l = t & 63;

  for (int i = t; i < 800; i += 256) inv_l[i] = invq[q0*100 + i];

  int npr = (w < 3) ? 9 : 8;
  int prs = ph*35 + w*9;

  float acc[8][9];
  #pragma unroll
  for (int q = 0; q < 8; q++)
    #pragma unroll
    for (int j = 0; j < 9; j++) acc[q][j] = 0.f;

  const float4* fq4 = (const float4*)(feat + (size_t)NS*6400);
  const float4* B4  = (const float4*)vptT;
  float4* A4 = (float4*)A;

  for (int c = 0; c < 5; c++){
    __syncthreads();
    int f0 = c * 1280;
    #pragma unroll
    for (int i = 0; i < 10; i++){
      int fi = i*256 + t;
      int q  = fi / 320, c4 = fi - q*320;
      float4 vv = fq4[(size_t)(q0+q)*1600 + (f0>>2) + c4];
      int fb = f0 + c4*4;
      float r0 = vv.x, r1 = vv.y, r2 = vv.z, r3 = vv.w;
      int p0 = fb % 100;
      int p1 = (fb+1) % 100;
      int p2 = (fb+2) % 100;
      int p3 = (fb+3) % 100;
      r0 *= inv_l[q*100 + p0];
      r1 *= inv_l[q*100 + p1];
      r2 *= inv_l[q*100 + p2];
      r3 *= inv_l[q*100 + p3];
      A4[q*320 + c4] = make_float4(r0, r1, r2, r3);
    }
    __syncthreads();
    for (int s = 0; s < 5; s++){
      float4 a4[8];
      #pragma unroll
      for (int q = 0; q < 8; q++) a4[q] = A4[q*320 + s*64 + l];
      #pragma unroll
      for (int j = 0; j < 9; j++){
        if (j < npr){
          float4 b4 = B4[(size_t)(prs+j)*1600 + (f0>>2) + s*64 + l];
          #pragma unroll
          for (int q = 0; q < 8; q++)
            acc[q][j] += a4[q].x*b4.x + a4[q].y*b4.y + a4[q].z*b4.z + a4[q].w*b4.w;
        }
      }
    }
  }
  #pragma unroll
  for (int q = 0; q < 8; q++)
    #pragma unroll
    for (int j = 0; j < 9; j++){
      if (j < npr){
        float s = redsum64(acc[q][j]);
        if (l == 0) sim[(q0+q)*NPAIR + prs + j] = s;
      }
    }
}

// ---------------- kM: per-(q,n) softmax over 14 views ----------------
__global__ __launch_bounds__(256) void kM(const float* __restrict__ sim,
                                          const float* __restrict__ vninv,
                                          const float* __restrict__ temp,
                                          float* __restrict__ pw){
  int t = blockIdx.x*256 + threadIdx.x;
  if (t >= NQ*NWAY) return;
  int q = t / NWAY, n = t - q*NWAY;
  float invT = 1.f / (temp[0] + 1e-6f);
  float s[PRJ];
  float m = -3.4e38f;
  #pragma unroll
  for (int v = 0; v < PRJ; v++){
    int pr = n*PRJ + v;
    s[v] = sim[q*NPAIR + pr] * vninv[pr] * invT;
    m = fmaxf(m, s[v]);
  }
  float sum = 0.f;
  #pragma unroll
  for (int v = 0; v < PRJ; v++){ s[v] = expf(s[v] - m); sum += s[v]; }
  float rs = 1.f / sum;
  #pragma unroll
  for (int v = 0; v < PRJ; v++) pw[q*NPAIR + n*PRJ + v] = s[v] * rs;
}

// ---------------- kSg: sg[q][n][p] = sigmoid(sum_v pw*M) ----------------
__global__ __launch_bounds__(512) void kSg(const float* __restrict__ pw,
                                           const float* __restrict__ MM,
                                           float* __restrict__ sg){
  int q = blockIdx.x, t = threadIdx.x;
  if (t >= 500) return;
  int n = t / 100, p = t - n*100;
  float s = 0.f;
  #pragma unroll
  for (int v = 0; v < PRJ; v++)
    s += pw[q*NPAIR + n*PRJ + v] * MM[(n*PRJ + v)*100 + p];
  sg[(size_t)q*500 + t] = 1.f / (1.f + expf(-s));
}

// ---------------- kP: proto_q via precomputed sg ----------------
__global__ __launch_bounds__(256) void kP(const float* __restrict__ vpt,
                                          const float* __restrict__ pw,
                                          const float* __restrict__ sg,
                                          float* __restrict__ pq){
  int b = blockIdx.x;
  int n = b >> 6;
  int qb = b & 63;
  int t = threadIdx.x, w = t >> 6, l = t & 63;
  int q0 = qb*16 + w*4;

  float wq[4][PRJ];
  #pragma unroll
  for (int j = 0; j < 4; j++)
    #pragma unroll
    for (int v = 0; v < PRJ; v++)
      wq[j][v] = pw[(q0+j)*NPAIR + n*PRJ + v];

  float acc[4] = {0.f, 0.f, 0.f, 0.f};
  const float* vb = vpt + (size_t)n * PRJ * 6400;
  for (int p = 0; p < PP; p++){
    float vv[PRJ];
    #pragma unroll
    for (int v = 0; v < PRJ; v++) vv[v] = vb[v*6400 + p*64 + l];
    #pragma unroll
    for (int j = 0; j < 4; j++){
      float dot = 0.f;
      #pragma unroll
      for (int v = 0; v < PRJ; v++) dot += wq[j][v] * vv[v];
      float sgv = sg[(size_t)(q0+j)*500 + n*100 + p];
      acc[j] += sgv * dot;
    }
  }
  #pragma unroll
  for (int j = 0; j < 4; j++)
    pq[((q0+j)*NWAY + n)*64 + l] = acc[j];
}

// ---------------- kF: per-query epilogue ----------------
__global__ __launch_bounds__(64) void kF(const float* __restrict__ qv,
                                         const float* __restrict__ pqw,
                                         const float* __restrict__ base,
                                         const float* __restrict__ Wq,
                                         const float* __restrict__ bq,
                                         const float* __restrict__ Wk,
                                         const float* __restrict__ bk,
                                         const float* __restrict__ gate,
                                         const int*   __restrict__ label,
                                         float* __restrict__ pred,
                                         float* __restrict__ cls,
                                         float* __restrict__ aln){
  __shared__ float qvl[64];
  __shared__ float qp[16];
  __shared__ float dl[64];
  int q = blockIdx.x, l = threadIdx.x;

  float qvv = qv[q*64 + l];
  qvl[l] = qvv;
  __syncthreads();
  float qss = redsum64(qvv*qvv);
  float qn8 = fmaxf(sqrtf(qss), 1e-8f);

  if (l < 16){
    float s = bq[l];
    #pragma unroll
    for (int d = 0; d < 64; d++) s += qvl[d] * Wq[d*16 + l];
    qp[l] = s;
  }
  __syncthreads();

  float wkq = 0.f;
  #pragma unroll
  for (int e = 0; e < 16; e++) wkq += Wk[l*16 + e] * qp[e];
  float qpb = 0.f;
  #pragma unroll
  for (int e = 0; e < 16; e++) qpb += qp[e] * bk[e];

  float pqv[NWAY], cosv[NWAY], sc[NWAY];
  #pragma unroll
  for (int n = 0; n < NWAY; n++){
    float x = pqw[(q*NWAY + n)*64 + l];
    pqv[n] = x;
    float dq = redsum64(qvv * x);
    float ps = redsum64(x * x);
    cosv[n] = dq / (qn8 * fmaxf(sqrtf(ps), 1e-8f));
    float sd = redsum64(x * wkq);
    sc[n] = (sd + qpb) * 0.25f;
  }

  float am = sc[0];
  #pragma unroll
  for (int n = 1; n < NWAY; n++) am = fmaxf(am, sc[n]);
  float ae[NWAY], asum = 0.f;
  #pragma unroll
  for (int n = 0; n < NWAY; n++){ ae[n] = expf(sc[n] - am); asum += ae[n]; }
  float rasum = 1.f / asum;

  float g0 = gate[0], g1 = gate[1], g2 = gate[2];
  float gm = fmaxf(fmaxf(g0, g1), g2);
  float e0 = expf(g0 - gm), e1 = expf(g1 - gm), e2 = expf(g2 - gm);
  float gs = 1.f / (e0 + e1 + e2);
  float b0 = (e0 + e1 + e2) * gs;
  float b1 = (e1 + e2) * gs;
  float b2 = e2 * gs;

  float cos2[NWAY];
  #pragma unroll
  for (int n = 0; n < NWAY; n++){
    float f  = pqv[n] * (ae[n] * rasum);
    float dd = fabsf(f - base[n*64 + l]);
    dl[l] = dd;
    __syncthreads();
    int rank = 0;
    #pragma unroll 8
    for (int j = 0; j < 64; j++){
      float dj = dl[j];
      rank += (dj > dd) || (dj == dd && j < l);
    }
    __syncthreads();
    float cw = (rank < 16) ? b0 : (rank < 32) ? b1 : (rank < 48) ? b2 : 0.f;
    float gl = f * cw;
    float gss = redsum64(gl * gl);
    float num = redsum64(qvv * gl);
    cos2[n] = num / (qn8 * fmaxf(sqrtf(gss), 1e-12f));
  }

  float mx = cos2[0];
  #pragma unroll
  for (int n = 1; n < NWAY; n++) mx = fmaxf(mx, cos2[n]);
  float pe[NWAY], psum = 0.f;
  #pragma unroll
  for (int n = 0; n < NWAY; n++){ pe[n] = expf(cos2[n] - mx); psum += pe[n]; }
  float rp = 1.f / psum;
  if (l == 0){
    #pragma unroll
    for (int n = 0; n < NWAY; n++) pred[q*NWAY + n] = pe[n] * rp;
  }

  int lab = label[q];
  float lm = LAMDA * mx;
  float lsum = 0.f;
  #pragma unroll
  for (int n = 0; n < NWAY; n++) lsum += expf(LAMDA * cos2[n] - lm);
  float c2l = cos2[0], cosl = cosv[0];
  #pragma unroll
  for (int n = 1; n < NWAY; n++){
    if (lab == n){ c2l = cos2[n]; cosl = cosv[n]; }
  }
  float clsv = (lm + logf(lsum)) - LAMDA * c2l;

  float sum5 = 0.f, minn = 3.4e38f;
  #pragma unroll
  for (int n = 0; n < NWAY; n++){
    sum5 += cosv[n];
    if (n != lab) minn = fminf(minn, cosv[n]);
  }
  float hn = (sum5 - cosl - minn) * (1.f/3.f);
  float al = fmaxf(hn - cosl + MARGIN, 0.f);
  if (l == 0){ cls[q] = clsv; aln[q] = al; }
}

// ---------------- kL: loss reduction ----------------
__global__ __launch_bounds__(256) void kL(const float* __restrict__ cls,
                                          const float* __restrict__ aln,
                                          float* __restrict__ out){
  __shared__ float r1[256], r2[256];
  int t = threadIdx.x;
  float s1 = 0.f, s2 = 0.f;
  for (int i = t; i < NQ; i += 256){ s1 += cls[i]; s2 += aln[i]; }
  r1[t] = s1; r2[t] = s2;
  __syncthreads();
  for (int o = 128; o > 0; o >>= 1){
    if (t < o){ r1[t] += r1[t + o]; r2[t] += r2[t + o]; }
    __syncthreads();
  }
  if (t == 0)
    out[NQ*NWAY] = r1[0]*(1.f/NQ) + 0.3f*(r2[0]*(1.f/NQ));
}

extern "C" void kernel_launch(void* const* d_in, const int* in_sizes, int n_in,
                              void* d_out, int out_size, void* d_ws, size_t ws_size,
                              hipStream_t stream){
  const float* feat = (const float*)d_in[0];
  const float* temp = (const float*)d_in[1];
  const float* gate = (const float*)d_in[2];
  const float* Wq   = (const float*)d_in[3];
  const float* bq   = (const float*)d_in[4];
  const float* Wk   = (const float*)d_in[5];
  const float* bk   = (const float*)d_in[6];
  const int*   lab  = (const int*)d_in[7];
  float* out = (float*)d_out;
  float* ws  = (float*)d_ws;

  float* vpt   = ws + VPT_OFF;
  float* vptT  = ws + VPTT_OFF;
  float* MMp   = ws + MM_OFF;
  float* vninv = ws + VNINV_OFF;
  float* psum  = ws + PSUM_OFF;
  float* base  = ws + BASE_OFF;
  float* qv    = ws + QV_OFF;
  float* invq  = ws + INVQ_OFF;
  float* sim   = ws + SIM_OFF;
  float* pw    = ws + PW_OFF;
  float* sg    = ws + SG_OFF;
  float* pq    = ws + PQ_OFF;
  float* cls   = ws + CLS_OFF;
  float* aln   = ws + ALN_OFF;

  hipLaunchKernelGGL(kV, dim3(NPAIR), dim3(256), 0, stream, feat, vpt, vptT, MMp, vninv, psum);
  hipLaunchKernelGGL(kB, dim3(1), dim3(320), 0, stream, psum, base);
  hipLaunchKernelGGL(kQ, dim3(NQ), dim3(256), 0, stream, feat, invq, qv);
  hipLaunchKernelGGL(kS, dim3(256), dim3(256), 0, stream, feat, invq, vptT, sim);
  hipLaunchKernelGGL(kM, dim3((NQ*NWAY + 255)/256), dim3(256), 0, stream, sim, vninv, temp, pw);
  hipLaunchKernelGGL(kSg, dim3(NQ), dim3(512), 0, stream, pw, MMp, sg);
  hipLaunchKernelGGL(kP, dim3(320), dim3(256), 0, stream, vpt, pw, sg, pq);
  hipLaunchKernelGGL(kF, dim3(NQ), dim3(64), 0, stream, qv, pq, base, Wq, bq, Wk, bk, gate, lab, out, cls, aln);
  hipLaunchKernelGGL(kL, dim3(1), dim3(256), 0, stream, cls, aln, out);
}

// Round 4
// 139.325 us; speedup vs baseline: 3.7061x; 1.3775x over previous
//
#include <hip/hip_runtime.h>
#include <math.h>

#define NWAY 5
#define KSHOT 5
#define PRJ 14
#define DD 64
#define PP 100
#define NQ 1024
#define NS 350
#define NPAIR 70
#define LAMDA 32.0f
#define MARGIN 0.3f
#define PSPLIT 4
#define PCHUNK 25

// ---- workspace layout (floats), ~11.4 MB ----
#define VPT_OFF   0          // [70][100][64]  = 448000
#define VPTT_OFF  448000     // [70][6400]     = 448000
#define MM_OFF    896000     // [70][100]      = 7000
#define VNINV_OFF 903000     // [70] pad 128
#define PSUM_OFF  903128     // [70][64] = 4480
#define BASE_OFF  907608     // [5][64]
#define QV_OFF    907928     // [1024][64] = 65536
#define INVQ_OFF  973464     // [1024][100] = 102400
#define SIM_OFF   1075864    // [1024][70] = 71680
#define PW_OFF    1147544    // [1024][70] = 71680
#define PQ4_OFF   1219224    // [4][1024][5][64] = 1310720
#define PQ_OFF    2529944    // [1024][5][64] = 327680
#define CLS_OFF   2857624    // [1024]
#define ALN_OFF   2858648    // [1024]

#define PQ_ELEMS (NQ*NWAY*64)

__device__ __forceinline__ float redsum64(float x){
  #pragma unroll
  for (int o = 1; o < 64; o <<= 1) x += __shfl_xor(x, o, 64);
  return x;
}

// ---------------- kV: support normalize + vpt + vptT + M + vninv + psum ----------------
__global__ __launch_bounds__(256) void kV(const float* __restrict__ feat,
                                          float* __restrict__ vpt,
                                          float* __restrict__ vptT,
                                          float* __restrict__ MM,
                                          float* __restrict__ vninv,
                                          float* __restrict__ psum){
  __shared__ float lds[64*101];
  __shared__ float inv[100];
  __shared__ float red[4];
  int pair = blockIdx.x;
  int n = pair / PRJ, v = pair - n*PRJ;
  int t = threadIdx.x;
  float acc[25];
  #pragma unroll
  for (int i = 0; i < 25; i++) acc[i] = 0.f;

  for (int k = 0; k < KSHOT; k++){
    int s = (n*KSHOT + k)*PRJ + v;
    const float* fp = feat + (size_t)s * 6400;
    #pragma unroll
    for (int i = 0; i < 25; i++){
      int j = t + 256*i;
      int d = j / 100, p = j - d*100;
      lds[d*101 + p] = fp[j];
    }
    __syncthreads();
    if (t < 100){
      float ss = 0.f;
      #pragma unroll
      for (int d = 0; d < 64; d++){ float x = lds[d*101 + t]; ss += x*x; }
      inv[t] = 1.f / fmaxf(sqrtf(ss), 1e-12f);
    }
    __syncthreads();
    #pragma unroll
    for (int i = 0; i < 25; i++){
      int j = t + 256*i;
      int p = j >> 6, d = j & 63;
      acc[i] += lds[d*101 + p] * inv[p];
    }
    __syncthreads();
  }
  float ssq = 0.f;
  #pragma unroll
  for (int i = 0; i < 25; i++){
    int j = t + 256*i;
    int p = j >> 6, d = j & 63;
    float val = acc[i] * 0.2f;
    vpt[(size_t)pair*6400 + j] = val;
    lds[d*101 + p] = val;
    ssq += val*val;
  }
  ssq = redsum64(ssq);
  if ((t & 63) == 0) red[t >> 6] = ssq;
  __syncthreads();
  if (t == 0){
    float tot = red[0] + red[1] + red[2] + red[3];
    vninv[pair] = 1.f / fmaxf(sqrtf(tot), 1e-12f);
  }
  #pragma unroll
  for (int i = 0; i < 25; i++){
    int f = t + 256*i;
    int d = f / 100;
    vptT[(size_t)pair*6400 + f] = lds[f + d];
  }
  if (t < 100){
    float s = 0.f;
    #pragma unroll
    for (int d = 0; d < 64; d++) s += lds[d*101 + t];
    MM[pair*100 + t] = s * (1.f/64.f);
  }
  if (t >= 128 && t < 192){
    int d = t - 128;
    float s = 0.f;
    #pragma unroll
    for (int p = 0; p < PP; p++) s += lds[d*101 + p];
    psum[pair*64 + d] = s;
  }
}

// ---------------- kB: tiny reduce of psum -> base ----------------
__global__ __launch_bounds__(320) void kB(const float* __restrict__ psum,
                                          float* __restrict__ base){
  int t = threadIdx.x;
  int n = t >> 6, d = t & 63;
  float s = 0.f;
  #pragma unroll
  for (int v = 0; v < PRJ; v++) s += psum[(n*PRJ + v)*64 + d];
  base[t] = s * (1.f/1400.f);
}

// ---------------- kQ: per-query inv norms + query_vec ----------------
__global__ __launch_bounds__(256) void kQ(const float* __restrict__ feat,
                                          float* __restrict__ invq,
                                          float* __restrict__ qv){
  __shared__ float lds[64*101];
  __shared__ float inv[100];
  int q = blockIdx.x, t = threadIdx.x;
  const float* fp = feat + (size_t)(NS + q) * 6400;
  #pragma unroll
  for (int i = 0; i < 25; i++){
    int j = t + 256*i;
    int d = j / 100, p = j - d*100;
    lds[d*101 + p] = fp[j];
  }
  __syncthreads();
  if (t < 100){
    float ss = 0.f;
    #pragma unroll
    for (int d = 0; d < 64; d++){ float x = lds[d*101 + t]; ss += x*x; }
    float iv = 1.f / fmaxf(sqrtf(ss), 1e-12f);
    inv[t] = iv;
    invq[q*100 + t] = iv;
  }
  __syncthreads();
  if (t < 64){
    float s = 0.f;
    for (int p = 0; p < PP; p++) s += lds[t*101 + p] * inv[p];
    qv[q*64 + t] = s * 0.01f;
  }
}

// ---------------- kS: sim = qn x vptT ----------------
__global__ __launch_bounds__(256) void kS(const float* __restrict__ feat,
                                          const float* __restrict__ invq,
                                          const float* __restrict__ vptT,
                                          float* __restrict__ sim){
  __shared__ float A[8*1280];
  __shared__ float inv_l[800];
  int b = blockIdx.x;
  int qg = b >> 1, ph = b & 1;
  int q0 = qg * 8;
  int t = threadIdx.x;
  int w = t >> 6, l = t & 63;

  for (int i = t; i < 800; i += 256) inv_l[i] = invq[q0*100 + i];

  int npr = (w < 3) ? 9 : 8;
  int prs = ph*35 + w*9;

  float acc[8][9];
  #pragma unroll
  for (int q = 0; q < 8; q++)
    #pragma unroll
    for (int j = 0; j < 9; j++) acc[q][j] = 0.f;

  const float4* fq4 = (const float4*)(feat + (size_t)NS*6400);
  const float4* B4  = (const float4*)vptT;
  float4* A4 = (float4*)A;

  for (int c = 0; c < 5; c++){
    __syncthreads();
    int f0 = c * 1280;
    #pragma unroll
    for (int i = 0; i < 10; i++){
      int fi = i*256 + t;
      int q  = fi / 320, c4 = fi - q*320;
      float4 vv = fq4[(size_t)(q0+q)*1600 + (f0>>2) + c4];
      int fb = f0 + c4*4;
      float r0 = vv.x, r1 = vv.y, r2 = vv.z, r3 = vv.w;
      int p0 = fb % 100;
      int p1 = (fb+1) % 100;
      int p2 = (fb+2) % 100;
      int p3 = (fb+3) % 100;
      r0 *= inv_l[q*100 + p0];
      r1 *= inv_l[q*100 + p1];
      r2 *= inv_l[q*100 + p2];
      r3 *= inv_l[q*100 + p3];
      A4[q*320 + c4] = make_float4(r0, r1, r2, r3);
    }
    __syncthreads();
    for (int s = 0; s < 5; s++){
      float4 a4[8];
      #pragma unroll
      for (int q = 0; q < 8; q++) a4[q] = A4[q*320 + s*64 + l];
      #pragma unroll
      for (int j = 0; j < 9; j++){
        if (j < npr){
          float4 b4 = B4[(size_t)(prs+j)*1600 + (f0>>2) + s*64 + l];
          #pragma unroll
          for (int q = 0; q < 8; q++)
            acc[q][j] += a4[q].x*b4.x + a4[q].y*b4.y + a4[q].z*b4.z + a4[q].w*b4.w;
        }
      }
    }
  }
  #pragma unroll
  for (int q = 0; q < 8; q++)
    #pragma unroll
    for (int j = 0; j < 9; j++){
      if (j < npr){
        float s = redsum64(acc[q][j]);
        if (l == 0) sim[(q0+q)*NPAIR + prs + j] = s;
      }
    }
}

// ---------------- kM: per-(q,n) softmax over 14 views ----------------
__global__ __launch_bounds__(256) void kM(const float* __restrict__ sim,
                                          const float* __restrict__ vninv,
                                          const float* __restrict__ temp,
                                          float* __restrict__ pw){
  int t = blockIdx.x*256 + threadIdx.x;
  if (t >= NQ*NWAY) return;
  int q = t / NWAY, n = t - q*NWAY;
  float invT = 1.f / (temp[0] + 1e-6f);
  float s[PRJ];
  float m = -3.4e38f;
  #pragma unroll
  for (int v = 0; v < PRJ; v++){
    int pr = n*PRJ + v;
    s[v] = sim[q*NPAIR + pr] * vninv[pr] * invT;
    m = fmaxf(m, s[v]);
  }
  float sum = 0.f;
  #pragma unroll
  for (int v = 0; v < PRJ; v++){ s[v] = expf(s[v] - m); sum += s[v]; }
  float rs = 1.f / sum;
  #pragma unroll
  for (int v = 0; v < PRJ; v++) pw[q*NPAIR + n*PRJ + v] = s[v] * rs;
}

// ---------------- kP v3: p-split 4x, sg computed inline, partial outputs ----------------
// grid 1280: b -> n = b/256; r = b%256; qb = r>>2 (16 q); s = r&3 (25 p's)
__global__ __launch_bounds__(256) void kP(const float* __restrict__ vpt,
                                          const float* __restrict__ pw,
                                          const float* __restrict__ MM,
                                          float* __restrict__ pq4){
  __shared__ float sgl[16][PCHUNK];
  int b = blockIdx.x;
  int n  = b / 256;
  int r  = b - n*256;
  int qb = r >> 2;
  int s  = r & 3;
  int p0 = s * PCHUNK;
  int t = threadIdx.x, w = t >> 6, l = t & 63;
  int q0 = qb*16 + w*4;

  float wq[4][PRJ];
  #pragma unroll
  for (int j = 0; j < 4; j++)
    #pragma unroll
    for (int v = 0; v < PRJ; v++)
      wq[j][v] = pw[(q0+j)*NPAIR + n*PRJ + v];

  // inline sg: sigmoid(sum_v pw*MM) for this block's 16 q x 25 p
  if (l < PCHUNK){
    #pragma unroll
    for (int j = 0; j < 4; j++){
      float ssg = 0.f;
      #pragma unroll
      for (int v = 0; v < PRJ; v++)
        ssg += wq[j][v] * MM[(n*PRJ + v)*100 + p0 + l];
      sgl[w*4 + j][l] = 1.f / (1.f + expf(-ssg));
    }
  }
  __syncthreads();

  float acc[4] = {0.f, 0.f, 0.f, 0.f};
  const float* vb = vpt + (size_t)n * PRJ * 6400;
  for (int pl = 0; pl < PCHUNK; pl++){
    int p = p0 + pl;
    float vv[PRJ];
    #pragma unroll
    for (int v = 0; v < PRJ; v++) vv[v] = vb[v*6400 + p*64 + l];
    #pragma unroll
    for (int j = 0; j < 4; j++){
      float dot = 0.f;
      #pragma unroll
      for (int v = 0; v < PRJ; v++) dot += wq[j][v] * vv[v];
      acc[j] += sgl[w*4 + j][pl] * dot;
    }
  }
  #pragma unroll
  for (int j = 0; j < 4; j++)
    pq4[(size_t)s*PQ_ELEMS + ((q0+j)*NWAY + n)*64 + l] = acc[j];
}

// ---------------- kPr: reduce 4 p-split partials ----------------
__global__ __launch_bounds__(256) void kPr(const float* __restrict__ pq4,
                                           float* __restrict__ pq){
  int idx = blockIdx.x*256 + threadIdx.x;
  float s = pq4[idx] + pq4[PQ_ELEMS + idx] + pq4[2*PQ_ELEMS + idx] + pq4[3*PQ_ELEMS + idx];
  pq[idx] = s;
}

// ---------------- kF: per-query epilogue ----------------
__global__ __launch_bounds__(64) void kF(const float* __restrict__ qv,
                                         const float* __restrict__ pqw,
                                         const float* __restrict__ base,
                                         const float* __restrict__ Wq,
                                         const float* __restrict__ bq,
                                         const float* __restrict__ Wk,
                                         const float* __restrict__ bk,
                                         const float* __restrict__ gate,
                                         const int*   __restrict__ label,
                                         float* __restrict__ pred,
                                         float* __restrict__ cls,
                                         float* __restrict__ aln){
  __shared__ float qvl[64];
  __shared__ float qp[16];
  __shared__ float dl[64];
  int q = blockIdx.x, l = threadIdx.x;

  float qvv = qv[q*64 + l];
  qvl[l] = qvv;
  __syncthreads();
  float qss = redsum64(qvv*qvv);
  float qn8 = fmaxf(sqrtf(qss), 1e-8f);

  if (l < 16){
    float s = bq[l];
    #pragma unroll
    for (int d = 0; d < 64; d++) s += qvl[d] * Wq[d*16 + l];
    qp[l] = s;
  }
  __syncthreads();

  float wkq = 0.f;
  #pragma unroll
  for (int e = 0; e < 16; e++) wkq += Wk[l*16 + e] * qp[e];
  float qpb = 0.f;
  #pragma unroll
  for (int e = 0; e < 16; e++) qpb += qp[e] * bk[e];

  float pqv[NWAY], cosv[NWAY], sc[NWAY];
  #pragma unroll
  for (int n = 0; n < NWAY; n++){
    float x = pqw[(q*NWAY + n)*64 + l];
    pqv[n] = x;
    float dq = redsum64(qvv * x);
    float ps = redsum64(x * x);
    cosv[n] = dq / (qn8 * fmaxf(sqrtf(ps), 1e-8f));
    float sd = redsum64(x * wkq);
    sc[n] = (sd + qpb) * 0.25f;
  }

  float am = sc[0];
  #pragma unroll
  for (int n = 1; n < NWAY; n++) am = fmaxf(am, sc[n]);
  float ae[NWAY], asum = 0.f;
  #pragma unroll
  for (int n = 0; n < NWAY; n++){ ae[n] = expf(sc[n] - am); asum += ae[n]; }
  float rasum = 1.f / asum;

  float g0 = gate[0], g1 = gate[1], g2 = gate[2];
  float gm = fmaxf(fmaxf(g0, g1), g2);
  float e0 = expf(g0 - gm), e1 = expf(g1 - gm), e2 = expf(g2 - gm);
  float gs = 1.f / (e0 + e1 + e2);
  float b0 = (e0 + e1 + e2) * gs;
  float b1 = (e1 + e2) * gs;
  float b2 = e2 * gs;

  float cos2[NWAY];
  #pragma unroll
  for (int n = 0; n < NWAY; n++){
    float f  = pqv[n] * (ae[n] * rasum);
    float dd = fabsf(f - base[n*64 + l]);
    dl[l] = dd;
    __syncthreads();
    int rank = 0;
    #pragma unroll 8
    for (int j = 0; j < 64; j++){
      float dj = dl[j];
      rank += (dj > dd) || (dj == dd && j < l);
    }
    __syncthreads();
    float cw = (rank < 16) ? b0 : (rank < 32) ? b1 : (rank < 48) ? b2 : 0.f;
    float gl = f * cw;
    float gss = redsum64(gl * gl);
    float num = redsum64(qvv * gl);
    cos2[n] = num / (qn8 * fmaxf(sqrtf(gss), 1e-12f));
  }

  float mx = cos2[0];
  #pragma unroll
  for (int n = 1; n < NWAY; n++) mx = fmaxf(mx, cos2[n]);
  float pe[NWAY], psum = 0.f;
  #pragma unroll
  for (int n = 0; n < NWAY; n++){ pe[n] = expf(cos2[n] - mx); psum += pe[n]; }
  float rp = 1.f / psum;
  if (l == 0){
    #pragma unroll
    for (int n = 0; n < NWAY; n++) pred[q*NWAY + n] = pe[n] * rp;
  }

  int lab = label[q];
  float lm = LAMDA * mx;
  float lsum = 0.f;
  #pragma unroll
  for (int n = 0; n < NWAY; n++) lsum += expf(LAMDA * cos2[n] - lm);
  float c2l = cos2[0], cosl = cosv[0];
  #pragma unroll
  for (int n = 1; n < NWAY; n++){
    if (lab == n){ c2l = cos2[n]; cosl = cosv[n]; }
  }
  float clsv = (lm + logf(lsum)) - LAMDA * c2l;

  float sum5 = 0.f, minn = 3.4e38f;
  #pragma unroll
  for (int n = 0; n < NWAY; n++){
    sum5 += cosv[n];
    if (n != lab) minn = fminf(minn, cosv[n]);
  }
  float hn = (sum5 - cosl - minn) * (1.f/3.f);
  float al = fmaxf(hn - cosl + MARGIN, 0.f);
  if (l == 0){ cls[q] = clsv; aln[q] = al; }
}

// ---------------- kL: loss reduction ----------------
__global__ __launch_bounds__(256) void kL(const float* __restrict__ cls,
                                          const float* __restrict__ aln,
                                          float* __restrict__ out){
  __shared__ float r1[256], r2[256];
  int t = threadIdx.x;
  float s1 = 0.f, s2 = 0.f;
  for (int i = t; i < NQ; i += 256){ s1 += cls[i]; s2 += aln[i]; }
  r1[t] = s1; r2[t] = s2;
  __syncthreads();
  for (int o = 128; o > 0; o >>= 1){
    if (t < o){ r1[t] += r1[t + o]; r2[t] += r2[t + o]; }
    __syncthreads();
  }
  if (t == 0)
    out[NQ*NWAY] = r1[0]*(1.f/NQ) + 0.3f*(r2[0]*(1.f/NQ));
}

extern "C" void kernel_launch(void* const* d_in, const int* in_sizes, int n_in,
                              void* d_out, int out_size, void* d_ws, size_t ws_size,
                              hipStream_t stream){
  const float* feat = (const float*)d_in[0];
  const float* temp = (const float*)d_in[1];
  const float* gate = (const float*)d_in[2];
  const float* Wq   = (const float*)d_in[3];
  const float* bq   = (const float*)d_in[4];
  const float* Wk   = (const float*)d_in[5];
  const float* bk   = (const float*)d_in[6];
  const int*   lab  = (const int*)d_in[7];
  float* out = (float*)d_out;
  float* ws  = (float*)d_ws;

  float* vpt   = ws + VPT_OFF;
  float* vptT  = ws + VPTT_OFF;
  float* MMp   = ws + MM_OFF;
  float* vninv = ws + VNINV_OFF;
  float* psum  = ws + PSUM_OFF;
  float* base  = ws + BASE_OFF;
  float* qv    = ws + QV_OFF;
  float* invq  = ws + INVQ_OFF;
  float* sim   = ws + SIM_OFF;
  float* pw    = ws + PW_OFF;
  float* pq4   = ws + PQ4_OFF;
  float* pq    = ws + PQ_OFF;
  float* cls   = ws + CLS_OFF;
  float* aln   = ws + ALN_OFF;

  hipLaunchKernelGGL(kV, dim3(NPAIR), dim3(256), 0, stream, feat, vpt, vptT, MMp, vninv, psum);
  hipLaunchKernelGGL(kB, dim3(1), dim3(320), 0, stream, psum, base);
  hipLaunchKernelGGL(kQ, dim3(NQ), dim3(256), 0, stream, feat, invq, qv);
  hipLaunchKernelGGL(kS, dim3(256), dim3(256), 0, stream, feat, invq, vptT, sim);
  hipLaunchKernelGGL(kM, dim3((NQ*NWAY + 255)/256), dim3(256), 0, stream, sim, vninv, temp, pw);
  hipLaunchKernelGGL(kP, dim3(NWAY*256), dim3(256), 0, stream, vpt, pw, MMp, pq4);
  hipLaunchKernelGGL(kPr, dim3(PQ_ELEMS/256), dim3(256), 0, stream, pq4, pq);
  hipLaunchKernelGGL(kF, dim3(NQ), dim3(64), 0, stream, qv, pq, base, Wq, bq, Wk, bk, gate, lab, out, cls, aln);
  hipLaunchKernelGGL(kL, dim3(1), dim3(256), 0, stream, cls, aln, out);
}